// Round 13
// baseline (345.148 us; speedup 1.0000x reference)
//
#include <hip/hip_runtime.h>
#include <math.h>

#define Hh 8
#define DKc 128
#define DVc 256
#define CHUNKc 64
#define GLNf 16.0f
#define EPSf 1e-5f

#define Bb 4
#define Tt 2048
#define Dd 2048
#define KDIM 1024
#define VDIM 2048
#define Mrows 8192
#define NCHUNK 32
#define NBH 32

typedef short bf16x8 __attribute__((ext_vector_type(8)));
typedef float f32x4 __attribute__((ext_vector_type(4)));
typedef ushort ushort8v __attribute__((ext_vector_type(8)));

__device__ inline ushort f2bf(float f) {
  unsigned u = __float_as_uint(f);
  unsigned r = (u + 0x7fffu + ((u >> 16) & 1u)) >> 16;
  return (ushort)r;
}
__device__ inline float bf2f(ushort u) {
  return __uint_as_float(((unsigned)u) << 16);
}
// log_sigmoid(g) = min(g,0) - log(1 + exp(-|g|)); branch-free, hw v_exp/v_log.
__device__ inline float logsig(float g) {
  return fminf(g, 0.f) - __logf(1.f + __expf(-fabsf(g)));
}

// ---------------- RMSNorm + bf16 cast: one block per row ----------------
__global__ __launch_bounds__(256) void rmsnorm_kernel(const float* __restrict__ seg,
                                                      const float* __restrict__ norm_w,
                                                      ushort* __restrict__ xb) {
  int row = blockIdx.x;
  int t = threadIdx.x;
  const float4* p = (const float4*)(seg + (size_t)row * Dd);
  float4 a = p[t];
  float4 b = p[t + 256];
  float ss = a.x * a.x + a.y * a.y + a.z * a.z + a.w * a.w +
             b.x * b.x + b.y * b.y + b.z * b.z + b.w * b.w;
#pragma unroll
  for (int off = 32; off > 0; off >>= 1) ss += __shfl_down(ss, off);
  __shared__ float red[4];
  if ((t & 63) == 0) red[t >> 6] = ss;
  __syncthreads();
  float tot = red[0] + red[1] + red[2] + red[3];
  float scale = rsqrtf(tot * (1.0f / (float)Dd) + EPSf);
  const float4* w4 = (const float4*)norm_w;
  float4 wa = w4[t], wb = w4[t + 256];
  ushort4 oa, ob;
  oa.x = f2bf(a.x * scale * wa.x);
  oa.y = f2bf(a.y * scale * wa.y);
  oa.z = f2bf(a.z * scale * wa.z);
  oa.w = f2bf(a.w * scale * wa.w);
  ob.x = f2bf(b.x * scale * wb.x);
  ob.y = f2bf(b.y * scale * wb.y);
  ob.z = f2bf(b.z * scale * wb.z);
  ob.w = f2bf(b.w * scale * wb.w);
  ushort4* o4 = (ushort4*)(xb + (size_t)row * Dd);
  o4[t] = oa;
  o4[t + 256] = ob;
}

// --- fused transpose: W_allT[3200][2048] = [Wv^T(2048) ; Wk^T(1024) ; Wg1^T pad(128)] ---
__global__ __launch_bounds__(256) void transpose_all_kernel(const float* __restrict__ Wv,
                                                            const float* __restrict__ Wk,
                                                            const float* __restrict__ Wg1,
                                                            ushort* __restrict__ Wall) {
  const int K = 2048;
  __shared__ float tile[32][33];
  int k0 = blockIdx.x * 32;
  int n0 = blockIdx.y * 32;
  const float* src;
  int N, stride, nb;
  if (n0 < 2048) {
    src = Wv; N = 2048; stride = 2048; nb = n0;
  } else if (n0 < 3072) {
    src = Wk; N = 1024; stride = 1024; nb = n0 - 2048;
  } else {
    src = Wg1; N = 16; stride = 16; nb = n0 - 3072;
  }
  int tx = threadIdx.x & 31;
  int ty = threadIdx.x >> 5;
#pragma unroll
  for (int i = 0; i < 32; i += 8) {
    int k = k0 + ty + i;
    int n = nb + tx;
    tile[ty + i][tx] = (n < N) ? src[(size_t)k * stride + n] : 0.0f;
  }
  __syncthreads();
#pragma unroll
  for (int i = 0; i < 32; i += 8) {
    Wall[(size_t)(n0 + ty + i) * K + k0 + tx] = f2bf(tile[tx][ty + i]);
  }
}

// --- per-batch bf16 transpose v2: 64x64 tiles, ushort4 global, stride-65 LDS ---
__global__ __launch_bounds__(256) void transpose_x_kernel(const ushort* __restrict__ xb,
                                                          ushort* __restrict__ xT) {
  __shared__ ushort tile[64 * 65];
  int b = blockIdx.z;
  int t0 = blockIdx.x * 64;
  int d0 = blockIdx.y * 64;
  int tx = threadIdx.x & 15;   // d quad
  int ty = threadIdx.x >> 4;   // 0..15
#pragma unroll
  for (int i = 0; i < 4; ++i) {
    int t = i * 16 + ty;
    ushort4 v = *(const ushort4*)(xb + ((size_t)b * Tt + t0 + t) * Dd + d0 + tx * 4);
    tile[t * 65 + tx * 4 + 0] = v.x;
    tile[t * 65 + tx * 4 + 1] = v.y;
    tile[t * 65 + tx * 4 + 2] = v.z;
    tile[t * 65 + tx * 4 + 3] = v.w;
  }
  __syncthreads();
  int tw = threadIdx.x & 15;   // t quad
  int dw = threadIdx.x >> 4;   // 0..15
#pragma unroll
  for (int j = 0; j < 4; ++j) {
    int d = j * 16 + dw;
    ushort4 o;
    o.x = tile[(tw * 4 + 0) * 65 + d];
    o.y = tile[(tw * 4 + 1) * 65 + d];
    o.z = tile[(tw * 4 + 2) * 65 + d];
    o.w = tile[(tw * 4 + 3) * 65 + d];
    *(ushort4*)(xT + ((size_t)b * Dd + d0 + d) * Tt + t0 + tw * 4) = o;
  }
}

// ------- GEMM1 (128x64 tile — best measured, R10): xb[8192][2048] @ Wallk[1152][2048]^T -------
// bn<16 -> kT[bh][kd][t], else g1. grid dim3(64,18): bm fastest => A-tile sharers
// (idx stride 64 == 0 mod 8) on same XCD. 1152 blocks = 4.5/CU.
__global__ __launch_bounds__(256) void gemm_kg_kernel(const ushort* __restrict__ A,
                                                      const ushort* __restrict__ Wallk,
                                                      ushort* __restrict__ kT,
                                                      float* __restrict__ g1) {
  __shared__ __align__(16) ushort As[128 * 32];
  __shared__ __align__(16) ushort Bs[64 * 32];
  int bm = blockIdx.x;
  int bn = blockIdx.y;  // 0..17
  int wave = threadIdx.x >> 6;
  int lane = threadIdx.x & 63;
  int wm = wave >> 1, wn = wave & 1;
  int lrow = lane & 15;
  int quad = lane >> 4;
  int rowInChunk = lane >> 2;
  int kElem = (lane & 3) * 8;

  f32x4 acc[4][2] = {};
  for (int kk = 0; kk < Dd; kk += 32) {
#pragma unroll
    for (int r = 0; r < 2; ++r) {
      int chunk = wave * 2 + r;
      int arow = chunk * 16 + rowInChunk;
      const ushort* ga = A + ((size_t)(bm * 128 + arow)) * Dd + kk + kElem;
      __builtin_amdgcn_global_load_lds((__attribute__((address_space(1))) void*)ga,
                                       (__attribute__((address_space(3))) void*)(As + chunk * 512),
                                       16, 0, 0);
    }
    {
      int brow = wave * 16 + rowInChunk;
      const ushort* gb = Wallk + ((size_t)(bn * 64 + brow)) * Dd + kk + kElem;
      __builtin_amdgcn_global_load_lds((__attribute__((address_space(1))) void*)gb,
                                       (__attribute__((address_space(3))) void*)(Bs + wave * 512),
                                       16, 0, 0);
    }
    __syncthreads();
    bf16x8 af[4], bfr[2];
#pragma unroll
    for (int i = 0; i < 4; ++i) af[i] = *(const bf16x8*)(As + (wm * 64 + i * 16 + lrow) * 32 + quad * 8);
#pragma unroll
    for (int j = 0; j < 2; ++j) bfr[j] = *(const bf16x8*)(Bs + (wn * 32 + j * 16 + lrow) * 32 + quad * 8);
#pragma unroll
    for (int i = 0; i < 4; ++i)
#pragma unroll
      for (int j = 0; j < 2; ++j)
        acc[i][j] = __builtin_amdgcn_mfma_f32_16x16x32_bf16(af[i], bfr[j], acc[i][j], 0, 0, 0);
    __syncthreads();
  }

#pragma unroll
  for (int i = 0; i < 4; ++i) {
    int m0 = bm * 128 + wm * 64 + i * 16 + quad * 4;
    int b = m0 >> 11, tloc = m0 & 2047;
#pragma unroll
    for (int j = 0; j < 2; ++j) {
      int col = bn * 64 + wn * 32 + j * 16 + lrow;
      if (bn < 16) {  // k: kT[bh][kd][t]
        int h = col >> 7, kd = col & 127;
        ushort4 o;
        o.x = f2bf(acc[i][j][0]);
        o.y = f2bf(acc[i][j][1]);
        o.z = f2bf(acc[i][j][2]);
        o.w = f2bf(acc[i][j][3]);
        *(ushort4*)(kT + ((size_t)((b * 8 + h) * 128 + kd)) * 2048 + tloc) = o;
      } else {  // g1 fp32 [8192][128]; col in [1024,1152)
        int cg = col - 1024;
#pragma unroll
        for (int rg = 0; rg < 4; ++rg)
          g1[(size_t)(m0 + rg) * 128 + cg] = acc[i][j][rg];
      }
    }
  }
}

// ------- GEMM2 split-K=2 (128x128 tile): Yp[ks][bh][kd][d] = kwT[bh](:,Kslice) @ xT[b](:,Kslice)^T -------
// 1024 blocks (4/CU queue). XCD swizzle: idx%8 == bh%8 — A-tile sharers colocate.
__global__ __launch_bounds__(256) void gemm_y_kernel(const ushort* __restrict__ kwT,
                                                     const ushort* __restrict__ xT,
                                                     ushort* __restrict__ Yp) {
  __shared__ __align__(16) ushort As[128 * 32];
  __shared__ __align__(16) ushort Bs[128 * 32];
  int q = blockIdx.x >> 3;             // 0..127
  int bn = q & 15;                     // d tile 0..15
  int ks = (q >> 4) & 1;               // t-half 0..1
  int bh = (blockIdx.x & 7) + 8 * (q >> 5);
  int b = bh >> 3;
  const ushort* A = kwT + (size_t)bh * DKc * Tt;
  const ushort* B = xT + (size_t)b * Dd * Tt;
  int wave = threadIdx.x >> 6;
  int lane = threadIdx.x & 63;
  int wm = wave >> 1, wn = wave & 1;
  int lrow = lane & 15;
  int quad = lane >> 4;
  int rowInChunk = lane >> 2;
  int kElem = (lane & 3) * 8;

  f32x4 acc[4][4] = {};
  int kk0 = ks * 1024;
  for (int kk = kk0; kk < kk0 + 1024; kk += 32) {
#pragma unroll
    for (int r = 0; r < 2; ++r) {
      int chunk = wave * 2 + r;
      int arow = chunk * 16 + rowInChunk;
      const ushort* ga = A + (size_t)arow * Tt + kk + kElem;
      const ushort* gb = B + ((size_t)(bn * 128 + arow)) * Tt + kk + kElem;
      __builtin_amdgcn_global_load_lds((__attribute__((address_space(1))) void*)ga,
                                       (__attribute__((address_space(3))) void*)(As + chunk * 512),
                                       16, 0, 0);
      __builtin_amdgcn_global_load_lds((__attribute__((address_space(1))) void*)gb,
                                       (__attribute__((address_space(3))) void*)(Bs + chunk * 512),
                                       16, 0, 0);
    }
    __syncthreads();
    bf16x8 af[4], bfr[4];
#pragma unroll
    for (int i = 0; i < 4; ++i) af[i] = *(const bf16x8*)(As + (wm * 64 + i * 16 + lrow) * 32 + quad * 8);
#pragma unroll
    for (int j = 0; j < 4; ++j) bfr[j] = *(const bf16x8*)(Bs + (wn * 64 + j * 16 + lrow) * 32 + quad * 8);
#pragma unroll
    for (int i = 0; i < 4; ++i)
#pragma unroll
      for (int j = 0; j < 4; ++j)
        acc[i][j] = __builtin_amdgcn_mfma_f32_16x16x32_bf16(af[i], bfr[j], acc[i][j], 0, 0, 0);
    __syncthreads();
  }

  ushort* Yo = Yp + (size_t)ks * NBH * DKc * Dd;
#pragma unroll
  for (int i = 0; i < 4; ++i) {
    int row0 = wm * 64 + i * 16 + quad * 4;  // kd
#pragma unroll
    for (int j = 0; j < 4; ++j) {
      int col = bn * 128 + wn * 64 + j * 16 + lrow;  // d
#pragma unroll
      for (int rg = 0; rg < 4; ++rg)
        Yo[((size_t)bh * DKc + row0 + rg) * Dd + col] = f2bf(acc[i][j][rg]);
    }
  }
}

// ------- reduce_y: Y = Yp0 + Yp1 (bf16), 8.4M elements -------
__global__ __launch_bounds__(256) void reduce_y_kernel(const ushort* __restrict__ Yp,
                                                       ushort* __restrict__ Y) {
  size_t i8 = (size_t)blockIdx.x * 256 + threadIdx.x;  // ushort8 index
  const size_t HALF = (size_t)NBH * DKc * Dd;          // 8388608 elements
  ushort8v a = *(const ushort8v*)(Yp + i8 * 8);
  ushort8v c = *(const ushort8v*)(Yp + HALF + i8 * 8);
  ushort8v o;
#pragma unroll
  for (int j = 0; j < 8; ++j) o[j] = f2bf(bf2f(a[j]) + bf2f(c[j]));
  *(ushort8v*)(Y + i8 * 8) = o;
}

// ------- GEMM3 split-K (128x128 — best measured, R9): Spart[ks][bh] = Y[bh] @ WvT_h^T -------
// XCD swizzle: idx%8 == bh%8 == h — colocates Y A-tile users and WvT_h sharers. 256 blocks.
__global__ __launch_bounds__(256) void gemm_out_sk_kernel(const ushort* __restrict__ Y,
                                                          const ushort* __restrict__ WvT,
                                                          float* __restrict__ Spart) {
  __shared__ __align__(16) ushort As[128 * 32];
  __shared__ __align__(16) ushort Bs[128 * 32];
  int q = blockIdx.x >> 3;             // 0..31
  int inner = q & 7;
  int bn = inner >> 2;                 // vv tile 0..1
  int ks = inner & 3;                  // split-K 0..3
  int bh = (blockIdx.x & 7) + 8 * (q >> 3);
  int h = bh & 7;
  const ushort* A = Y + (size_t)bh * DKc * Dd;
  const ushort* B = WvT + (size_t)(h * DVc + bn * 128) * Dd;
  int wave = threadIdx.x >> 6;
  int lane = threadIdx.x & 63;
  int wm = wave >> 1, wn = wave & 1;
  int lrow = lane & 15;
  int quad = lane >> 4;
  int rowInChunk = lane >> 2;
  int kElem = (lane & 3) * 8;

  f32x4 acc[4][4] = {};
  int kk0 = ks * 512;
  for (int kk = kk0; kk < kk0 + 512; kk += 32) {
#pragma unroll
    for (int r = 0; r < 2; ++r) {
      int chunk = wave * 2 + r;
      int arow = chunk * 16 + rowInChunk;
      const ushort* ga = A + (size_t)arow * Dd + kk + kElem;
      const ushort* gb = B + (size_t)arow * Dd + kk + kElem;
      __builtin_amdgcn_global_load_lds((__attribute__((address_space(1))) void*)ga,
                                       (__attribute__((address_space(3))) void*)(As + chunk * 512),
                                       16, 0, 0);
      __builtin_amdgcn_global_load_lds((__attribute__((address_space(1))) void*)gb,
                                       (__attribute__((address_space(3))) void*)(Bs + chunk * 512),
                                       16, 0, 0);
    }
    __syncthreads();
    bf16x8 af[4], bfr[4];
#pragma unroll
    for (int i = 0; i < 4; ++i) af[i] = *(const bf16x8*)(As + (wm * 64 + i * 16 + lrow) * 32 + quad * 8);
#pragma unroll
    for (int j = 0; j < 4; ++j) bfr[j] = *(const bf16x8*)(Bs + (wn * 64 + j * 16 + lrow) * 32 + quad * 8);
#pragma unroll
    for (int i = 0; i < 4; ++i)
#pragma unroll
      for (int j = 0; j < 4; ++j)
        acc[i][j] = __builtin_amdgcn_mfma_f32_16x16x32_bf16(af[i], bfr[j], acc[i][j], 0, 0, 0);
    __syncthreads();
  }

  float* Sp = Spart + ((size_t)ks * NBH + bh) * (DKc * DVc);
#pragma unroll
  for (int i = 0; i < 4; ++i) {
    int row0 = wm * 64 + i * 16 + quad * 4;  // kd
#pragma unroll
    for (int j = 0; j < 4; ++j) {
      int col = bn * 128 + wn * 64 + j * 16 + lrow;  // vv
#pragma unroll
      for (int rg = 0; rg < 4; ++rg)
        Sp[(size_t)(row0 + rg) * DVc + col] = acc[i][j][rg];
    }
  }
}

// ------------- out = S0*eBtot + sum_ks Spart -------------
__global__ __launch_bounds__(256) void reduce_kernel(const float* __restrict__ Spart,
                                                     const float* __restrict__ eBtot,
                                                     const float* __restrict__ S0,
                                                     float* __restrict__ out) {
  int i4 = blockIdx.x * 256 + threadIdx.x;
  int idx = i4 * 4;
  int bh = idx >> 15;
  int kd = (idx >> 8) & 127;
  float e = eBtot[bh * DKc + kd];
  float4 a = ((const float4*)S0)[i4];
  float4 p0 = ((const float4*)Spart)[i4];
  float4 p1 = ((const float4*)Spart)[i4 + 262144];
  float4 p2 = ((const float4*)Spart)[i4 + 524288];
  float4 p3 = ((const float4*)Spart)[i4 + 786432];
  float4 r;
  r.x = a.x * e + p0.x + p1.x + p2.x + p3.x;
  r.y = a.y * e + p0.y + p1.y + p2.y + p3.y;
  r.z = a.z * e + p0.z + p1.z + p2.z + p3.z;
  r.w = a.w * e + p0.w + p1.w + p2.w + p3.w;
  ((float4*)out)[i4] = r;
}

// ------------- chunk gate sums: L[bh][n][kd] = sum_c logsig(g1@Wg2col + b)/GLN -------------
__global__ __launch_bounds__(128) void chunksum_kernel(const float* __restrict__ g1,
                                                       const float* __restrict__ Wg2,
                                                       const float* __restrict__ bg2,
                                                       float* __restrict__ L) {
  int n = blockIdx.x, bh = blockIdx.y;
  int b = bh >> 3, h = bh & 7;
  int t = threadIdx.x;  // kd
  int kdg = h * DKc + t;
  int trow = b * Tt + n * CHUNKc;
  __shared__ float g1s[CHUNKc * 16];
#pragma unroll
  for (int i = 0; i < 8; ++i) {
    int flat = i * 128 + t;
    int c = flat >> 4, r = flat & 15;
    g1s[flat] = g1[(size_t)(trow + c) * 128 + r];
  }
  float wc[16];
#pragma unroll
  for (int r = 0; r < 16; ++r) wc[r] = Wg2[r * KDIM + kdg];
  float bias = bg2[kdg];
  __syncthreads();
  float sum = 0.f;
  for (int c = 0; c < CHUNKc; ++c) {
    float dot = bias;
#pragma unroll
    for (int r = 0; r < 16; ++r) dot = fmaf(g1s[c * 16 + r], wc[r], dot);
    sum += logsig(dot) * (1.0f / GLNf);
  }
  L[((size_t)bh * NCHUNK + n) * DKc + t] = sum;
}

// ------------- weights: kwT[bh][kd][t] = bf16(k * exp(Btot - B_t)) in place; eBtot -------------
__global__ __launch_bounds__(128) void weight_kernel(const float* __restrict__ g1,
                                                     const float* __restrict__ Wg2,
                                                     const float* __restrict__ bg2,
                                                     const float* __restrict__ L,
                                                     ushort* __restrict__ kwT,
                                                     float* __restrict__ eBtot) {
  int n = blockIdx.x, bh = blockIdx.y;
  int b = bh >> 3, h = bh & 7;
  int t = threadIdx.x;  // kd
  int kdg = h * DKc + t;
  int trow = b * Tt + n * CHUNKc;
  __shared__ float g1s[CHUNKc * 16];
#pragma unroll
  for (int i = 0; i < 8; ++i) {
    int flat = i * 128 + t;
    int c = flat >> 4, r = flat & 15;
    g1s[flat] = g1[(size_t)(trow + c) * 128 + r];
  }
  float wc[16];
#pragma unroll
  for (int r = 0; r < 16; ++r) wc[r] = Wg2[r * KDIM + kdg];
  float bias = bg2[kdg];

  float suffix = 0.f, Ln = 0.f, Btot = 0.f;
#pragma unroll
  for (int m = 0; m < NCHUNK; ++m) {
    float Lm = L[((size_t)bh * NCHUNK + m) * DKc + t];
    if (m > n) suffix += Lm;
    if (m == n) Ln = Lm;
    Btot += Lm;
  }
  if (n == 0) eBtot[bh * DKc + t] = __expf(Btot);
  __syncthreads();

  float run = 0.f;
  size_t obase = ((size_t)bh * DKc + t) * (size_t)Tt + (size_t)n * CHUNKc;
  for (int cg = 0; cg < 8; ++cg) {
    ushort8v kw8;
    ushort8v k8 = *(const ushort8v*)(kwT + obase + cg * 8);
#pragma unroll
    for (int j = 0; j < 8; ++j) {
      int c = cg * 8 + j;
      float dot = bias;
#pragma unroll
      for (int r = 0; r < 16; ++r) dot = fmaf(g1s[c * 16 + r], wc[r], dot);
      run += logsig(dot) * (1.0f / GLNf);
      float w = __expf(suffix + Ln - run);  // exponent <= 0 always
      kw8[j] = f2bf(bf2f(k8[j]) * w);
    }
    *(ushort8v*)(kwT + obase + cg * 8) = kw8;
  }
}

extern "C" void kernel_launch(void* const* d_in, const int* in_sizes, int n_in,
                              void* d_out, int out_size, void* d_ws, size_t ws_size,
                              hipStream_t stream) {
  const float* seg = (const float*)d_in[0];
  const float* norm_w = (const float*)d_in[1];
  const float* Wk = (const float*)d_in[2];
  const float* Wv = (const float*)d_in[3];
  const float* Wg1 = (const float*)d_in[4];
  const float* Wg2 = (const float*)d_in[5];
  const float* bg2 = (const float*)d_in[6];
  const float* S0 = (const float*)d_in[7];
  float* out = (float*)d_out;
  char* ws = (char*)d_ws;

  // ---- workspace 93.65 MiB (proven available R6-R12) ----
  // regA 32MiB: xb bf16[8192][2048] -> (dead after gemm_kg + transpose_x)
  //             Yp bf16[2][32][128][2048] -> (dead after reduce_y) Spart f32[4][32][128][256]
  // regB 32MiB: xT bf16[4][2048][2048]
  // regD 16MiB: kT bf16[32][128][2048] -> kwT (in-place RMW) -> (dead after gemm_y)
  //             Y bf16[32][128][2048] (written by reduce_y)
  // regC 12.5MiB: W_allT bf16[3200][2048]; then Lbuf f32[32][32][128], eBtot f32[32][128]
  // d_out: g1 f32[8192][128] (dead before reduce writes d_out)
  char* regA = ws;
  char* regB = ws + (size_t)32 * 1024 * 1024;
  char* regD = ws + (size_t)64 * 1024 * 1024;
  char* regC = ws + (size_t)80 * 1024 * 1024;
  float* Lbuf = (float*)(regC + 13107200);
  float* eBtot = (float*)(regC + 13107200 + 524288);

  ushort* xb = (ushort*)regA;
  ushort* Yp = (ushort*)regA;                  // after xb dead (2 x 16 MiB halves)
  float* Spart = (float*)regA;                 // after Yp dead (post reduce_y)
  ushort* xT = (ushort*)regB;
  ushort* kwT = (ushort*)regD;
  ushort* Yfin = (ushort*)regD;                // after kwT dead (post gemm_y)
  ushort* Wall = (ushort*)regC;
  ushort* Wallk = Wall + (size_t)2048 * 2048;  // rows 2048.. = [Wk^T ; Wg1^T]
  float* g1buf = (float*)d_out;

  rmsnorm_kernel<<<Mrows, 256, 0, stream>>>(seg, norm_w, xb);
  transpose_all_kernel<<<dim3(64, 100), 256, 0, stream>>>(Wv, Wk, Wg1, Wall);
  transpose_x_kernel<<<dim3(32, 32, 4), 256, 0, stream>>>(xb, xT);
  gemm_kg_kernel<<<dim3(64, 18), 256, 0, stream>>>(xb, Wallk, kwT, g1buf);
  chunksum_kernel<<<dim3(NCHUNK, NBH), 128, 0, stream>>>(g1buf, Wg2, bg2, Lbuf);
  weight_kernel<<<dim3(NCHUNK, NBH), 128, 0, stream>>>(g1buf, Wg2, bg2, Lbuf, kwT, eBtot);
  gemm_y_kernel<<<1024, 256, 0, stream>>>(kwT, xT, Yp);
  reduce_y_kernel<<<4096, 256, 0, stream>>>(Yp, Yfin);        // Y -> regD (kwT dead)
  gemm_out_sk_kernel<<<256, 256, 0, stream>>>(Yfin, Wall, Spart);
  reduce_kernel<<<1024, 256, 0, stream>>>(Spart, eBtot, S0, out);
}

// Round 14
// 317.643 us; speedup vs baseline: 1.0866x; 1.0866x over previous
//
#include <hip/hip_runtime.h>
#include <math.h>

#define Hh 8
#define DKc 128
#define DVc 256
#define CHUNKc 64
#define GLNf 16.0f
#define EPSf 1e-5f

#define Bb 4
#define Tt 2048
#define Dd 2048
#define KDIM 1024
#define VDIM 2048
#define Mrows 8192
#define NCHUNK 32
#define NBH 32

typedef short bf16x8 __attribute__((ext_vector_type(8)));
typedef float f32x4 __attribute__((ext_vector_type(4)));
typedef ushort ushort8v __attribute__((ext_vector_type(8)));

__device__ inline ushort f2bf(float f) {
  unsigned u = __float_as_uint(f);
  unsigned r = (u + 0x7fffu + ((u >> 16) & 1u)) >> 16;
  return (ushort)r;
}
__device__ inline float bf2f(ushort u) {
  return __uint_as_float(((unsigned)u) << 16);
}
// log_sigmoid(g) = min(g,0) - log(1 + exp(-|g|)); branch-free, hw v_exp/v_log.
__device__ inline float logsig(float g) {
  return fminf(g, 0.f) - __logf(1.f + __expf(-fabsf(g)));
}

// ---------------- RMSNorm + bf16 cast: one block per row ----------------
__global__ __launch_bounds__(256) void rmsnorm_kernel(const float* __restrict__ seg,
                                                      const float* __restrict__ norm_w,
                                                      ushort* __restrict__ xb) {
  int row = blockIdx.x;
  int t = threadIdx.x;
  const float4* p = (const float4*)(seg + (size_t)row * Dd);
  float4 a = p[t];
  float4 b = p[t + 256];
  float ss = a.x * a.x + a.y * a.y + a.z * a.z + a.w * a.w +
             b.x * b.x + b.y * b.y + b.z * b.z + b.w * b.w;
#pragma unroll
  for (int off = 32; off > 0; off >>= 1) ss += __shfl_down(ss, off);
  __shared__ float red[4];
  if ((t & 63) == 0) red[t >> 6] = ss;
  __syncthreads();
  float tot = red[0] + red[1] + red[2] + red[3];
  float scale = rsqrtf(tot * (1.0f / (float)Dd) + EPSf);
  const float4* w4 = (const float4*)norm_w;
  float4 wa = w4[t], wb = w4[t + 256];
  ushort4 oa, ob;
  oa.x = f2bf(a.x * scale * wa.x);
  oa.y = f2bf(a.y * scale * wa.y);
  oa.z = f2bf(a.z * scale * wa.z);
  oa.w = f2bf(a.w * scale * wa.w);
  ob.x = f2bf(b.x * scale * wb.x);
  ob.y = f2bf(b.y * scale * wb.y);
  ob.z = f2bf(b.z * scale * wb.z);
  ob.w = f2bf(b.w * scale * wb.w);
  ushort4* o4 = (ushort4*)(xb + (size_t)row * Dd);
  o4[t] = oa;
  o4[t + 256] = ob;
}

// --- fused transpose: W_allT[3200][2048] = [Wv^T(2048) ; Wk^T(1024) ; Wg1^T pad(128)] ---
__global__ __launch_bounds__(256) void transpose_all_kernel(const float* __restrict__ Wv,
                                                            const float* __restrict__ Wk,
                                                            const float* __restrict__ Wg1,
                                                            ushort* __restrict__ Wall) {
  const int K = 2048;
  __shared__ float tile[32][33];
  int k0 = blockIdx.x * 32;
  int n0 = blockIdx.y * 32;
  const float* src;
  int N, stride, nb;
  if (n0 < 2048) {
    src = Wv; N = 2048; stride = 2048; nb = n0;
  } else if (n0 < 3072) {
    src = Wk; N = 1024; stride = 1024; nb = n0 - 2048;
  } else {
    src = Wg1; N = 16; stride = 16; nb = n0 - 3072;
  }
  int tx = threadIdx.x & 31;
  int ty = threadIdx.x >> 5;
#pragma unroll
  for (int i = 0; i < 32; i += 8) {
    int k = k0 + ty + i;
    int n = nb + tx;
    tile[ty + i][tx] = (n < N) ? src[(size_t)k * stride + n] : 0.0f;
  }
  __syncthreads();
#pragma unroll
  for (int i = 0; i < 32; i += 8) {
    Wall[(size_t)(n0 + ty + i) * K + k0 + tx] = f2bf(tile[tx][ty + i]);
  }
}

// --- per-batch bf16 transpose v2: 64x64 tiles, ushort4 global, stride-65 LDS ---
__global__ __launch_bounds__(256) void transpose_x_kernel(const ushort* __restrict__ xb,
                                                          ushort* __restrict__ xT) {
  __shared__ ushort tile[64 * 65];
  int b = blockIdx.z;
  int t0 = blockIdx.x * 64;
  int d0 = blockIdx.y * 64;
  int tx = threadIdx.x & 15;   // d quad
  int ty = threadIdx.x >> 4;   // 0..15
#pragma unroll
  for (int i = 0; i < 4; ++i) {
    int t = i * 16 + ty;
    ushort4 v = *(const ushort4*)(xb + ((size_t)b * Tt + t0 + t) * Dd + d0 + tx * 4);
    tile[t * 65 + tx * 4 + 0] = v.x;
    tile[t * 65 + tx * 4 + 1] = v.y;
    tile[t * 65 + tx * 4 + 2] = v.z;
    tile[t * 65 + tx * 4 + 3] = v.w;
  }
  __syncthreads();
  int tw = threadIdx.x & 15;   // t quad
  int dw = threadIdx.x >> 4;   // 0..15
#pragma unroll
  for (int j = 0; j < 4; ++j) {
    int d = j * 16 + dw;
    ushort4 o;
    o.x = tile[(tw * 4 + 0) * 65 + d];
    o.y = tile[(tw * 4 + 1) * 65 + d];
    o.z = tile[(tw * 4 + 2) * 65 + d];
    o.w = tile[(tw * 4 + 3) * 65 + d];
    *(ushort4*)(xT + ((size_t)b * Dd + d0 + d) * Tt + t0 + tw * 4) = o;
  }
}

// ------- GEMM1 (128x64 tile, BK=64 half-major LDS): xb[8192][2048] @ Wallk[1152][2048]^T -------
// As[2][128][32]: two 32-wide K-halves stacked, each with 64B row stride (bank-safe,
// global_load_lds-contiguous: one 1024B chunk = 16 rows x 32 elems of one half).
// 16 MFMA/wave per barrier pair (2x R10). bn<16 -> kT[bh][kd][t], else g1.
// grid dim3(64,18): bm fastest => A-tile sharers on same XCD.
__global__ __launch_bounds__(256) void gemm_kg_kernel(const ushort* __restrict__ A,
                                                      const ushort* __restrict__ Wallk,
                                                      ushort* __restrict__ kT,
                                                      float* __restrict__ g1) {
  __shared__ __align__(16) ushort As[2 * 128 * 32];  // 16 KB
  __shared__ __align__(16) ushort Bs[2 * 64 * 32];   //  8 KB
  int bm = blockIdx.x;
  int bn = blockIdx.y;  // 0..17
  int wave = threadIdx.x >> 6;
  int lane = threadIdx.x & 63;
  int wm = wave >> 1, wn = wave & 1;
  int lrow = lane & 15;
  int quad = lane >> 4;
  int rowIn = lane >> 2;          // 0..15 (16 rows per staging chunk)
  int eIn = (lane & 3) * 8;       // 0,8,16,24

  f32x4 acc[4][2] = {};
  for (int kk = 0; kk < Dd; kk += 64) {
    // A: 16 chunks (8 rowbases x 2 halves); wave issues 4
#pragma unroll
    for (int r = 0; r < 4; ++r) {
      int i = wave * 4 + r;          // 0..15
      int half = i & 1;
      int rowbase = (i >> 1) * 16;   // 0..112
      const ushort* ga = A + ((size_t)(bm * 128 + rowbase + rowIn)) * Dd + kk + half * 32 + eIn;
      __builtin_amdgcn_global_load_lds((__attribute__((address_space(1))) void*)ga,
                                       (__attribute__((address_space(3))) void*)(As + (half * 128 + rowbase) * 32),
                                       16, 0, 0);
    }
    // B: 8 chunks (4 rowbases x 2 halves); wave issues 2
#pragma unroll
    for (int r = 0; r < 2; ++r) {
      int i = wave * 2 + r;          // 0..7
      int half = i & 1;
      int rowbase = (i >> 1) * 16;   // 0..48
      const ushort* gb = Wallk + ((size_t)(bn * 64 + rowbase + rowIn)) * Dd + kk + half * 32 + eIn;
      __builtin_amdgcn_global_load_lds((__attribute__((address_space(1))) void*)gb,
                                       (__attribute__((address_space(3))) void*)(Bs + (half * 64 + rowbase) * 32),
                                       16, 0, 0);
    }
    __syncthreads();
#pragma unroll
    for (int h = 0; h < 2; ++h) {
      bf16x8 af[4], bfr[2];
#pragma unroll
      for (int i = 0; i < 4; ++i)
        af[i] = *(const bf16x8*)(As + (h * 128 + wm * 64 + i * 16 + lrow) * 32 + quad * 8);
#pragma unroll
      for (int j = 0; j < 2; ++j)
        bfr[j] = *(const bf16x8*)(Bs + (h * 64 + wn * 32 + j * 16 + lrow) * 32 + quad * 8);
#pragma unroll
      for (int i = 0; i < 4; ++i)
#pragma unroll
        for (int j = 0; j < 2; ++j)
          acc[i][j] = __builtin_amdgcn_mfma_f32_16x16x32_bf16(af[i], bfr[j], acc[i][j], 0, 0, 0);
    }
    __syncthreads();
  }

#pragma unroll
  for (int i = 0; i < 4; ++i) {
    int m0 = bm * 128 + wm * 64 + i * 16 + quad * 4;
    int b = m0 >> 11, tloc = m0 & 2047;
#pragma unroll
    for (int j = 0; j < 2; ++j) {
      int col = bn * 64 + wn * 32 + j * 16 + lrow;
      if (bn < 16) {  // k: kT[bh][kd][t]
        int h = col >> 7, kd = col & 127;
        ushort4 o;
        o.x = f2bf(acc[i][j][0]);
        o.y = f2bf(acc[i][j][1]);
        o.z = f2bf(acc[i][j][2]);
        o.w = f2bf(acc[i][j][3]);
        *(ushort4*)(kT + ((size_t)((b * 8 + h) * 128 + kd)) * 2048 + tloc) = o;
      } else {  // g1 fp32 [8192][128]; col in [1024,1152)
        int cg = col - 1024;
#pragma unroll
        for (int rg = 0; rg < 4; ++rg)
          g1[(size_t)(m0 + rg) * 128 + cg] = acc[i][j][rg];
      }
    }
  }
}

// ------- GEMM2 (128x128 tile — best measured, R9/R12): Y[bh][kd][d] = kwT[bh] @ xT[b]^T -------
// XCD swizzle: idx%8 == bh%8 — the 16 bn-blocks sharing one kwT A-tile colocate. 512 blocks.
__global__ __launch_bounds__(256) void gemm_y_kernel(const ushort* __restrict__ kwT,
                                                     const ushort* __restrict__ xT,
                                                     ushort* __restrict__ Y) {
  __shared__ __align__(16) ushort As[128 * 32];
  __shared__ __align__(16) ushort Bs[128 * 32];
  int q = blockIdx.x >> 3;             // 0..63
  int bn = q & 15;                     // d tile 0..15
  int bh = (blockIdx.x & 7) + 8 * (q >> 4);
  int b = bh >> 3;
  const ushort* A = kwT + (size_t)bh * DKc * Tt;
  const ushort* B = xT + (size_t)b * Dd * Tt;
  int wave = threadIdx.x >> 6;
  int lane = threadIdx.x & 63;
  int wm = wave >> 1, wn = wave & 1;
  int lrow = lane & 15;
  int quad = lane >> 4;
  int rowInChunk = lane >> 2;
  int kElem = (lane & 3) * 8;

  f32x4 acc[4][4] = {};
  for (int kk = 0; kk < Tt; kk += 32) {
#pragma unroll
    for (int r = 0; r < 2; ++r) {
      int chunk = wave * 2 + r;
      int arow = chunk * 16 + rowInChunk;
      const ushort* ga = A + (size_t)arow * Tt + kk + kElem;
      const ushort* gb = B + ((size_t)(bn * 128 + arow)) * Tt + kk + kElem;
      __builtin_amdgcn_global_load_lds((__attribute__((address_space(1))) void*)ga,
                                       (__attribute__((address_space(3))) void*)(As + chunk * 512),
                                       16, 0, 0);
      __builtin_amdgcn_global_load_lds((__attribute__((address_space(1))) void*)gb,
                                       (__attribute__((address_space(3))) void*)(Bs + chunk * 512),
                                       16, 0, 0);
    }
    __syncthreads();
    bf16x8 af[4], bfr[4];
#pragma unroll
    for (int i = 0; i < 4; ++i) af[i] = *(const bf16x8*)(As + (wm * 64 + i * 16 + lrow) * 32 + quad * 8);
#pragma unroll
    for (int j = 0; j < 4; ++j) bfr[j] = *(const bf16x8*)(Bs + (wn * 64 + j * 16 + lrow) * 32 + quad * 8);
#pragma unroll
    for (int i = 0; i < 4; ++i)
#pragma unroll
      for (int j = 0; j < 4; ++j)
        acc[i][j] = __builtin_amdgcn_mfma_f32_16x16x32_bf16(af[i], bfr[j], acc[i][j], 0, 0, 0);
    __syncthreads();
  }

#pragma unroll
  for (int i = 0; i < 4; ++i) {
    int row0 = wm * 64 + i * 16 + quad * 4;  // kd
#pragma unroll
    for (int j = 0; j < 4; ++j) {
      int col = bn * 128 + wn * 64 + j * 16 + lrow;  // d
#pragma unroll
      for (int rg = 0; rg < 4; ++rg)
        Y[((size_t)bh * DKc + row0 + rg) * Dd + col] = f2bf(acc[i][j][rg]);
    }
  }
}

// ------- GEMM3 split-K (128x128 — best measured, R9/R12): Spart[ks][bh] = Y[bh] @ WvT_h^T -------
// XCD swizzle: idx%8 == bh%8 == h — colocates Y A-tile users and WvT_h sharers. 256 blocks.
__global__ __launch_bounds__(256) void gemm_out_sk_kernel(const ushort* __restrict__ Y,
                                                          const ushort* __restrict__ WvT,
                                                          float* __restrict__ Spart) {
  __shared__ __align__(16) ushort As[128 * 32];
  __shared__ __align__(16) ushort Bs[128 * 32];
  int q = blockIdx.x >> 3;             // 0..31
  int inner = q & 7;
  int bn = inner >> 2;                 // vv tile 0..1
  int ks = inner & 3;                  // split-K 0..3
  int bh = (blockIdx.x & 7) + 8 * (q >> 3);
  int h = bh & 7;
  const ushort* A = Y + (size_t)bh * DKc * Dd;
  const ushort* B = WvT + (size_t)(h * DVc + bn * 128) * Dd;
  int wave = threadIdx.x >> 6;
  int lane = threadIdx.x & 63;
  int wm = wave >> 1, wn = wave & 1;
  int lrow = lane & 15;
  int quad = lane >> 4;
  int rowInChunk = lane >> 2;
  int kElem = (lane & 3) * 8;

  f32x4 acc[4][4] = {};
  int kk0 = ks * 512;
  for (int kk = kk0; kk < kk0 + 512; kk += 32) {
#pragma unroll
    for (int r = 0; r < 2; ++r) {
      int chunk = wave * 2 + r;
      int arow = chunk * 16 + rowInChunk;
      const ushort* ga = A + (size_t)arow * Dd + kk + kElem;
      const ushort* gb = B + (size_t)arow * Dd + kk + kElem;
      __builtin_amdgcn_global_load_lds((__attribute__((address_space(1))) void*)ga,
                                       (__attribute__((address_space(3))) void*)(As + chunk * 512),
                                       16, 0, 0);
      __builtin_amdgcn_global_load_lds((__attribute__((address_space(1))) void*)gb,
                                       (__attribute__((address_space(3))) void*)(Bs + chunk * 512),
                                       16, 0, 0);
    }
    __syncthreads();
    bf16x8 af[4], bfr[4];
#pragma unroll
    for (int i = 0; i < 4; ++i) af[i] = *(const bf16x8*)(As + (wm * 64 + i * 16 + lrow) * 32 + quad * 8);
#pragma unroll
    for (int j = 0; j < 4; ++j) bfr[j] = *(const bf16x8*)(Bs + (wn * 64 + j * 16 + lrow) * 32 + quad * 8);
#pragma unroll
    for (int i = 0; i < 4; ++i)
#pragma unroll
      for (int j = 0; j < 4; ++j)
        acc[i][j] = __builtin_amdgcn_mfma_f32_16x16x32_bf16(af[i], bfr[j], acc[i][j], 0, 0, 0);
    __syncthreads();
  }

  float* Sp = Spart + ((size_t)ks * NBH + bh) * (DKc * DVc);
#pragma unroll
  for (int i = 0; i < 4; ++i) {
    int row0 = wm * 64 + i * 16 + quad * 4;  // kd
#pragma unroll
    for (int j = 0; j < 4; ++j) {
      int col = bn * 128 + wn * 64 + j * 16 + lrow;  // vv
#pragma unroll
      for (int rg = 0; rg < 4; ++rg)
        Sp[(size_t)(row0 + rg) * DVc + col] = acc[i][j][rg];
    }
  }
}

// ------------- out = S0*eBtot + sum_ks Spart -------------
__global__ __launch_bounds__(256) void reduce_kernel(const float* __restrict__ Spart,
                                                     const float* __restrict__ eBtot,
                                                     const float* __restrict__ S0,
                                                     float* __restrict__ out) {
  int i4 = blockIdx.x * 256 + threadIdx.x;
  int idx = i4 * 4;
  int bh = idx >> 15;
  int kd = (idx >> 8) & 127;
  float e = eBtot[bh * DKc + kd];
  float4 a = ((const float4*)S0)[i4];
  float4 p0 = ((const float4*)Spart)[i4];
  float4 p1 = ((const float4*)Spart)[i4 + 262144];
  float4 p2 = ((const float4*)Spart)[i4 + 524288];
  float4 p3 = ((const float4*)Spart)[i4 + 786432];
  float4 r;
  r.x = a.x * e + p0.x + p1.x + p2.x + p3.x;
  r.y = a.y * e + p0.y + p1.y + p2.y + p3.y;
  r.z = a.z * e + p0.z + p1.z + p2.z + p3.z;
  r.w = a.w * e + p0.w + p1.w + p2.w + p3.w;
  ((float4*)out)[i4] = r;
}

// ------------- chunk gate sums: L[bh][n][kd] = sum_c logsig(g1@Wg2col + b)/GLN -------------
__global__ __launch_bounds__(128) void chunksum_kernel(const float* __restrict__ g1,
                                                       const float* __restrict__ Wg2,
                                                       const float* __restrict__ bg2,
                                                       float* __restrict__ L) {
  int n = blockIdx.x, bh = blockIdx.y;
  int b = bh >> 3, h = bh & 7;
  int t = threadIdx.x;  // kd
  int kdg = h * DKc + t;
  int trow = b * Tt + n * CHUNKc;
  __shared__ float g1s[CHUNKc * 16];
#pragma unroll
  for (int i = 0; i < 8; ++i) {
    int flat = i * 128 + t;
    int c = flat >> 4, r = flat & 15;
    g1s[flat] = g1[(size_t)(trow + c) * 128 + r];
  }
  float wc[16];
#pragma unroll
  for (int r = 0; r < 16; ++r) wc[r] = Wg2[r * KDIM + kdg];
  float bias = bg2[kdg];
  __syncthreads();
  float sum = 0.f;
  for (int c = 0; c < CHUNKc; ++c) {
    float dot = bias;
#pragma unroll
    for (int r = 0; r < 16; ++r) dot = fmaf(g1s[c * 16 + r], wc[r], dot);
    sum += logsig(dot) * (1.0f / GLNf);
  }
  L[((size_t)bh * NCHUNK + n) * DKc + t] = sum;
}

// ------------- weights: kwT[bh][kd][t] = bf16(k * exp(Btot - B_t)) in place; eBtot -------------
__global__ __launch_bounds__(128) void weight_kernel(const float* __restrict__ g1,
                                                     const float* __restrict__ Wg2,
                                                     const float* __restrict__ bg2,
                                                     const float* __restrict__ L,
                                                     ushort* __restrict__ kwT,
                                                     float* __restrict__ eBtot) {
  int n = blockIdx.x, bh = blockIdx.y;
  int b = bh >> 3, h = bh & 7;
  int t = threadIdx.x;  // kd
  int kdg = h * DKc + t;
  int trow = b * Tt + n * CHUNKc;
  __shared__ float g1s[CHUNKc * 16];
#pragma unroll
  for (int i = 0; i < 8; ++i) {
    int flat = i * 128 + t;
    int c = flat >> 4, r = flat & 15;
    g1s[flat] = g1[(size_t)(trow + c) * 128 + r];
  }
  float wc[16];
#pragma unroll
  for (int r = 0; r < 16; ++r) wc[r] = Wg2[r * KDIM + kdg];
  float bias = bg2[kdg];

  float suffix = 0.f, Ln = 0.f, Btot = 0.f;
#pragma unroll
  for (int m = 0; m < NCHUNK; ++m) {
    float Lm = L[((size_t)bh * NCHUNK + m) * DKc + t];
    if (m > n) suffix += Lm;
    if (m == n) Ln = Lm;
    Btot += Lm;
  }
  if (n == 0) eBtot[bh * DKc + t] = __expf(Btot);
  __syncthreads();

  float run = 0.f;
  size_t obase = ((size_t)bh * DKc + t) * (size_t)Tt + (size_t)n * CHUNKc;
  for (int cg = 0; cg < 8; ++cg) {
    ushort8v kw8;
    ushort8v k8 = *(const ushort8v*)(kwT + obase + cg * 8);
#pragma unroll
    for (int j = 0; j < 8; ++j) {
      int c = cg * 8 + j;
      float dot = bias;
#pragma unroll
      for (int r = 0; r < 16; ++r) dot = fmaf(g1s[c * 16 + r], wc[r], dot);
      run += logsig(dot) * (1.0f / GLNf);
      float w = __expf(suffix + Ln - run);  // exponent <= 0 always
      kw8[j] = f2bf(bf2f(k8[j]) * w);
    }
    *(ushort8v*)(kwT + obase + cg * 8) = kw8;
  }
}

extern "C" void kernel_launch(void* const* d_in, const int* in_sizes, int n_in,
                              void* d_out, int out_size, void* d_ws, size_t ws_size,
                              hipStream_t stream) {
  const float* seg = (const float*)d_in[0];
  const float* norm_w = (const float*)d_in[1];
  const float* Wk = (const float*)d_in[2];
  const float* Wv = (const float*)d_in[3];
  const float* Wg1 = (const float*)d_in[4];
  const float* Wg2 = (const float*)d_in[5];
  const float* bg2 = (const float*)d_in[6];
  const float* S0 = (const float*)d_in[7];
  float* out = (float*)d_out;
  char* ws = (char*)d_ws;

  // ---- workspace 93.65 MiB (proven available R6-R13) — exact R12 layout ----
  // regA 32MiB: xb bf16[8192][2048] -> (dead after gemm_kg + transpose_x) Y bf16[32][128][2048]
  // regB 32MiB: xT bf16[4][2048][2048]
  // regD 16MiB: kT bf16[32][128][2048] -> kwT (in-place RMW) -> (dead after gemm_y)
  //             Spart f32[4][32][128][256]
  // regC 12.5MiB: W_allT bf16[3200][2048]; then Lbuf f32[32][32][128], eBtot f32[32][128]
  // d_out: g1 f32[8192][128] (dead before reduce writes d_out)
  char* regA = ws;
  char* regB = ws + (size_t)32 * 1024 * 1024;
  char* regD = ws + (size_t)64 * 1024 * 1024;
  char* regC = ws + (size_t)80 * 1024 * 1024;
  float* Lbuf = (float*)(regC + 13107200);
  float* eBtot = (float*)(regC + 13107200 + 524288);

  ushort* xb = (ushort*)regA;
  ushort* Y = (ushort*)regA;                   // after xb dead
  ushort* xT = (ushort*)regB;
  ushort* kwT = (ushort*)regD;
  float* Spart = (float*)regD;                 // after kwT dead (post gemm_y)
  ushort* Wall = (ushort*)regC;
  ushort* Wallk = Wall + (size_t)2048 * 2048;  // rows 2048.. = [Wk^T ; Wg1^T]
  float* g1buf = (float*)d_out;

  rmsnorm_kernel<<<Mrows, 256, 0, stream>>>(seg, norm_w, xb);
  transpose_all_kernel<<<dim3(64, 100), 256, 0, stream>>>(Wv, Wk, Wg1, Wall);
  transpose_x_kernel<<<dim3(32, 32, 4), 256, 0, stream>>>(xb, xT);
  gemm_kg_kernel<<<dim3(64, 18), 256, 0, stream>>>(xb, Wallk, kwT, g1buf);
  chunksum_kernel<<<dim3(NCHUNK, NBH), 128, 0, stream>>>(g1buf, Wg2, bg2, Lbuf);
  weight_kernel<<<dim3(NCHUNK, NBH), 128, 0, stream>>>(g1buf, Wg2, bg2, Lbuf, kwT, eBtot);
  gemm_y_kernel<<<512, 256, 0, stream>>>(kwT, xT, Y);
  gemm_out_sk_kernel<<<256, 256, 0, stream>>>(Y, Wall, Spart);
  reduce_kernel<<<1024, 256, 0, stream>>>(Spart, eBtot, S0, out);
}

// Round 15
// 306.685 us; speedup vs baseline: 1.1254x; 1.0357x over previous
//
#include <hip/hip_runtime.h>
#include <math.h>

#define Hh 8
#define DKc 128
#define DVc 256
#define CHUNKc 64
#define GLNf 16.0f
#define EPSf 1e-5f

#define Bb 4
#define Tt 2048
#define Dd 2048
#define KDIM 1024
#define VDIM 2048
#define Mrows 8192
#define NCHUNK 32
#define NBH 32

typedef short bf16x8 __attribute__((ext_vector_type(8)));
typedef float f32x4 __attribute__((ext_vector_type(4)));
typedef ushort ushort8v __attribute__((ext_vector_type(8)));

__device__ inline ushort f2bf(float f) {
  unsigned u = __float_as_uint(f);
  unsigned r = (u + 0x7fffu + ((u >> 16) & 1u)) >> 16;
  return (ushort)r;
}
__device__ inline float bf2f(ushort u) {
  return __uint_as_float(((unsigned)u) << 16);
}
// log_sigmoid(g) = min(g,0) - log(1 + exp(-|g|)); branch-free, hw v_exp/v_log.
__device__ inline float logsig(float g) {
  return fminf(g, 0.f) - __logf(1.f + __expf(-fabsf(g)));
}

// ---------------- RMSNorm + bf16 cast: one block per row ----------------
__global__ __launch_bounds__(256) void rmsnorm_kernel(const float* __restrict__ seg,
                                                      const float* __restrict__ norm_w,
                                                      ushort* __restrict__ xb) {
  int row = blockIdx.x;
  int t = threadIdx.x;
  const float4* p = (const float4*)(seg + (size_t)row * Dd);
  float4 a = p[t];
  float4 b = p[t + 256];
  float ss = a.x * a.x + a.y * a.y + a.z * a.z + a.w * a.w +
             b.x * b.x + b.y * b.y + b.z * b.z + b.w * b.w;
#pragma unroll
  for (int off = 32; off > 0; off >>= 1) ss += __shfl_down(ss, off);
  __shared__ float red[4];
  if ((t & 63) == 0) red[t >> 6] = ss;
  __syncthreads();
  float tot = red[0] + red[1] + red[2] + red[3];
  float scale = rsqrtf(tot * (1.0f / (float)Dd) + EPSf);
  const float4* w4 = (const float4*)norm_w;
  float4 wa = w4[t], wb = w4[t + 256];
  ushort4 oa, ob;
  oa.x = f2bf(a.x * scale * wa.x);
  oa.y = f2bf(a.y * scale * wa.y);
  oa.z = f2bf(a.z * scale * wa.z);
  oa.w = f2bf(a.w * scale * wa.w);
  ob.x = f2bf(b.x * scale * wb.x);
  ob.y = f2bf(b.y * scale * wb.y);
  ob.z = f2bf(b.z * scale * wb.z);
  ob.w = f2bf(b.w * scale * wb.w);
  ushort4* o4 = (ushort4*)(xb + (size_t)row * Dd);
  o4[t] = oa;
  o4[t + 256] = ob;
}

// --- fused transpose: W_allT[3200][2048] = [Wv^T(2048) ; Wk^T(1024) ; Wg1^T pad(128)] ---
__global__ __launch_bounds__(256) void transpose_all_kernel(const float* __restrict__ Wv,
                                                            const float* __restrict__ Wk,
                                                            const float* __restrict__ Wg1,
                                                            ushort* __restrict__ Wall) {
  const int K = 2048;
  __shared__ float tile[32][33];
  int k0 = blockIdx.x * 32;
  int n0 = blockIdx.y * 32;
  const float* src;
  int N, stride, nb;
  if (n0 < 2048) {
    src = Wv; N = 2048; stride = 2048; nb = n0;
  } else if (n0 < 3072) {
    src = Wk; N = 1024; stride = 1024; nb = n0 - 2048;
  } else {
    src = Wg1; N = 16; stride = 16; nb = n0 - 3072;
  }
  int tx = threadIdx.x & 31;
  int ty = threadIdx.x >> 5;
#pragma unroll
  for (int i = 0; i < 32; i += 8) {
    int k = k0 + ty + i;
    int n = nb + tx;
    tile[ty + i][tx] = (n < N) ? src[(size_t)k * stride + n] : 0.0f;
  }
  __syncthreads();
#pragma unroll
  for (int i = 0; i < 32; i += 8) {
    Wall[(size_t)(n0 + ty + i) * K + k0 + tx] = f2bf(tile[tx][ty + i]);
  }
}

// --- per-batch bf16 transpose v2: 64x64 tiles, ushort4 global, stride-65 LDS ---
__global__ __launch_bounds__(256) void transpose_x_kernel(const ushort* __restrict__ xb,
                                                          ushort* __restrict__ xT) {
  __shared__ ushort tile[64 * 65];
  int b = blockIdx.z;
  int t0 = blockIdx.x * 64;
  int d0 = blockIdx.y * 64;
  int tx = threadIdx.x & 15;   // d quad
  int ty = threadIdx.x >> 4;   // 0..15
#pragma unroll
  for (int i = 0; i < 4; ++i) {
    int t = i * 16 + ty;
    ushort4 v = *(const ushort4*)(xb + ((size_t)b * Tt + t0 + t) * Dd + d0 + tx * 4);
    tile[t * 65 + tx * 4 + 0] = v.x;
    tile[t * 65 + tx * 4 + 1] = v.y;
    tile[t * 65 + tx * 4 + 2] = v.z;
    tile[t * 65 + tx * 4 + 3] = v.w;
  }
  __syncthreads();
  int tw = threadIdx.x & 15;   // t quad
  int dw = threadIdx.x >> 4;   // 0..15
#pragma unroll
  for (int j = 0; j < 4; ++j) {
    int d = j * 16 + dw;
    ushort4 o;
    o.x = tile[(tw * 4 + 0) * 65 + d];
    o.y = tile[(tw * 4 + 1) * 65 + d];
    o.z = tile[(tw * 4 + 2) * 65 + d];
    o.w = tile[(tw * 4 + 3) * 65 + d];
    *(ushort4*)(xT + ((size_t)b * Dd + d0 + d) * Tt + t0 + tw * 4) = o;
  }
}

// ------- GEMM1 (128x64 tile, BK=64 half-major LDS — R14 proven): xb @ Wallk^T -------
__global__ __launch_bounds__(256) void gemm_kg_kernel(const ushort* __restrict__ A,
                                                      const ushort* __restrict__ Wallk,
                                                      ushort* __restrict__ kT,
                                                      float* __restrict__ g1) {
  __shared__ __align__(16) ushort As[2 * 128 * 32];  // 16 KB
  __shared__ __align__(16) ushort Bs[2 * 64 * 32];   //  8 KB
  int bm = blockIdx.x;
  int bn = blockIdx.y;  // 0..17
  int wave = threadIdx.x >> 6;
  int lane = threadIdx.x & 63;
  int wm = wave >> 1, wn = wave & 1;
  int lrow = lane & 15;
  int quad = lane >> 4;
  int rowIn = lane >> 2;          // 0..15 (16 rows per staging chunk)
  int eIn = (lane & 3) * 8;       // 0,8,16,24

  f32x4 acc[4][2] = {};
  for (int kk = 0; kk < Dd; kk += 64) {
#pragma unroll
    for (int r = 0; r < 4; ++r) {
      int i = wave * 4 + r;          // 0..15
      int half = i & 1;
      int rowbase = (i >> 1) * 16;   // 0..112
      const ushort* ga = A + ((size_t)(bm * 128 + rowbase + rowIn)) * Dd + kk + half * 32 + eIn;
      __builtin_amdgcn_global_load_lds((__attribute__((address_space(1))) void*)ga,
                                       (__attribute__((address_space(3))) void*)(As + (half * 128 + rowbase) * 32),
                                       16, 0, 0);
    }
#pragma unroll
    for (int r = 0; r < 2; ++r) {
      int i = wave * 2 + r;          // 0..7
      int half = i & 1;
      int rowbase = (i >> 1) * 16;   // 0..48
      const ushort* gb = Wallk + ((size_t)(bn * 64 + rowbase + rowIn)) * Dd + kk + half * 32 + eIn;
      __builtin_amdgcn_global_load_lds((__attribute__((address_space(1))) void*)gb,
                                       (__attribute__((address_space(3))) void*)(Bs + (half * 64 + rowbase) * 32),
                                       16, 0, 0);
    }
    __syncthreads();
#pragma unroll
    for (int h = 0; h < 2; ++h) {
      bf16x8 af[4], bfr[2];
#pragma unroll
      for (int i = 0; i < 4; ++i)
        af[i] = *(const bf16x8*)(As + (h * 128 + wm * 64 + i * 16 + lrow) * 32 + quad * 8);
#pragma unroll
      for (int j = 0; j < 2; ++j)
        bfr[j] = *(const bf16x8*)(Bs + (h * 64 + wn * 32 + j * 16 + lrow) * 32 + quad * 8);
#pragma unroll
      for (int i = 0; i < 4; ++i)
#pragma unroll
        for (int j = 0; j < 2; ++j)
          acc[i][j] = __builtin_amdgcn_mfma_f32_16x16x32_bf16(af[i], bfr[j], acc[i][j], 0, 0, 0);
    }
    __syncthreads();
  }

#pragma unroll
  for (int i = 0; i < 4; ++i) {
    int m0 = bm * 128 + wm * 64 + i * 16 + quad * 4;
    int b = m0 >> 11, tloc = m0 & 2047;
#pragma unroll
    for (int j = 0; j < 2; ++j) {
      int col = bn * 64 + wn * 32 + j * 16 + lrow;
      if (bn < 16) {  // k: kT[bh][kd][t]
        int h = col >> 7, kd = col & 127;
        ushort4 o;
        o.x = f2bf(acc[i][j][0]);
        o.y = f2bf(acc[i][j][1]);
        o.z = f2bf(acc[i][j][2]);
        o.w = f2bf(acc[i][j][3]);
        *(ushort4*)(kT + ((size_t)((b * 8 + h) * 128 + kd)) * 2048 + tloc) = o;
      } else {  // g1 fp32 [8192][128]; col in [1024,1152)
        int cg = col - 1024;
#pragma unroll
        for (int rg = 0; rg < 4; ++rg)
          g1[(size_t)(m0 + rg) * 128 + cg] = acc[i][j][rg];
      }
    }
  }
}

// ------- GEMM2 (128x128 tile, BK=64 half-major): Y[bh][kd][d] = kwT[bh] @ xT[b]^T -------
// XCD swizzle: idx%8 == bh%8. 512 blocks. 32 MFMA per barrier pair (2x R12).
__global__ __launch_bounds__(256) void gemm_y_kernel(const ushort* __restrict__ kwT,
                                                     const ushort* __restrict__ xT,
                                                     ushort* __restrict__ Y) {
  __shared__ __align__(16) ushort As[2 * 128 * 32];  // 16 KB
  __shared__ __align__(16) ushort Bs[2 * 128 * 32];  // 16 KB
  int q = blockIdx.x >> 3;             // 0..63
  int bn = q & 15;                     // d tile 0..15
  int bh = (blockIdx.x & 7) + 8 * (q >> 4);
  int b = bh >> 3;
  const ushort* A = kwT + (size_t)bh * DKc * Tt;
  const ushort* B = xT + (size_t)b * Dd * Tt;
  int wave = threadIdx.x >> 6;
  int lane = threadIdx.x & 63;
  int wm = wave >> 1, wn = wave & 1;
  int lrow = lane & 15;
  int quad = lane >> 4;
  int rowIn = lane >> 2;
  int eIn = (lane & 3) * 8;

  f32x4 acc[4][4] = {};
  for (int kk = 0; kk < Tt; kk += 64) {
#pragma unroll
    for (int r = 0; r < 4; ++r) {
      int i = wave * 4 + r;          // 0..15
      int half = i & 1;
      int rowbase = (i >> 1) * 16;   // 0..112
      const ushort* ga = A + ((size_t)(rowbase + rowIn)) * Tt + kk + half * 32 + eIn;
      __builtin_amdgcn_global_load_lds((__attribute__((address_space(1))) void*)ga,
                                       (__attribute__((address_space(3))) void*)(As + (half * 128 + rowbase) * 32),
                                       16, 0, 0);
    }
#pragma unroll
    for (int r = 0; r < 4; ++r) {
      int i = wave * 4 + r;          // 0..15
      int half = i & 1;
      int rowbase = (i >> 1) * 16;   // 0..112
      const ushort* gb = B + ((size_t)(bn * 128 + rowbase + rowIn)) * Tt + kk + half * 32 + eIn;
      __builtin_amdgcn_global_load_lds((__attribute__((address_space(1))) void*)gb,
                                       (__attribute__((address_space(3))) void*)(Bs + (half * 128 + rowbase) * 32),
                                       16, 0, 0);
    }
    __syncthreads();
#pragma unroll
    for (int h = 0; h < 2; ++h) {
      bf16x8 af[4], bfr[4];
#pragma unroll
      for (int i = 0; i < 4; ++i)
        af[i] = *(const bf16x8*)(As + (h * 128 + wm * 64 + i * 16 + lrow) * 32 + quad * 8);
#pragma unroll
      for (int j = 0; j < 4; ++j)
        bfr[j] = *(const bf16x8*)(Bs + (h * 128 + wn * 64 + j * 16 + lrow) * 32 + quad * 8);
#pragma unroll
      for (int i = 0; i < 4; ++i)
#pragma unroll
        for (int j = 0; j < 4; ++j)
          acc[i][j] = __builtin_amdgcn_mfma_f32_16x16x32_bf16(af[i], bfr[j], acc[i][j], 0, 0, 0);
    }
    __syncthreads();
  }

#pragma unroll
  for (int i = 0; i < 4; ++i) {
    int row0 = wm * 64 + i * 16 + quad * 4;  // kd
#pragma unroll
    for (int j = 0; j < 4; ++j) {
      int col = bn * 128 + wn * 64 + j * 16 + lrow;  // d
#pragma unroll
      for (int rg = 0; rg < 4; ++rg)
        Y[((size_t)bh * DKc + row0 + rg) * Dd + col] = f2bf(acc[i][j][rg]);
    }
  }
}

// ------- GEMM3 split-K (128x128, BK=64 half-major): Spart[ks][bh] = Y[bh] @ WvT_h^T -------
// XCD swizzle: idx%8 == bh%8 == h. 256 blocks.
__global__ __launch_bounds__(256) void gemm_out_sk_kernel(const ushort* __restrict__ Y,
                                                          const ushort* __restrict__ WvT,
                                                          float* __restrict__ Spart) {
  __shared__ __align__(16) ushort As[2 * 128 * 32];  // 16 KB
  __shared__ __align__(16) ushort Bs[2 * 128 * 32];  // 16 KB
  int q = blockIdx.x >> 3;             // 0..31
  int inner = q & 7;
  int bn = inner >> 2;                 // vv tile 0..1
  int ks = inner & 3;                  // split-K 0..3
  int bh = (blockIdx.x & 7) + 8 * (q >> 3);
  int h = bh & 7;
  const ushort* A = Y + (size_t)bh * DKc * Dd;
  const ushort* B = WvT + (size_t)(h * DVc + bn * 128) * Dd;
  int wave = threadIdx.x >> 6;
  int lane = threadIdx.x & 63;
  int wm = wave >> 1, wn = wave & 1;
  int lrow = lane & 15;
  int quad = lane >> 4;
  int rowIn = lane >> 2;
  int eIn = (lane & 3) * 8;

  f32x4 acc[4][4] = {};
  int kk0 = ks * 512;
  for (int kk = kk0; kk < kk0 + 512; kk += 64) {
#pragma unroll
    for (int r = 0; r < 4; ++r) {
      int i = wave * 4 + r;
      int half = i & 1;
      int rowbase = (i >> 1) * 16;
      const ushort* ga = A + ((size_t)(rowbase + rowIn)) * Dd + kk + half * 32 + eIn;
      __builtin_amdgcn_global_load_lds((__attribute__((address_space(1))) void*)ga,
                                       (__attribute__((address_space(3))) void*)(As + (half * 128 + rowbase) * 32),
                                       16, 0, 0);
    }
#pragma unroll
    for (int r = 0; r < 4; ++r) {
      int i = wave * 4 + r;
      int half = i & 1;
      int rowbase = (i >> 1) * 16;
      const ushort* gb = B + ((size_t)(rowbase + rowIn)) * Dd + kk + half * 32 + eIn;
      __builtin_amdgcn_global_load_lds((__attribute__((address_space(1))) void*)gb,
                                       (__attribute__((address_space(3))) void*)(Bs + (half * 128 + rowbase) * 32),
                                       16, 0, 0);
    }
    __syncthreads();
#pragma unroll
    for (int h2 = 0; h2 < 2; ++h2) {
      bf16x8 af[4], bfr[4];
#pragma unroll
      for (int i = 0; i < 4; ++i)
        af[i] = *(const bf16x8*)(As + (h2 * 128 + wm * 64 + i * 16 + lrow) * 32 + quad * 8);
#pragma unroll
      for (int j = 0; j < 4; ++j)
        bfr[j] = *(const bf16x8*)(Bs + (h2 * 128 + wn * 64 + j * 16 + lrow) * 32 + quad * 8);
#pragma unroll
      for (int i = 0; i < 4; ++i)
#pragma unroll
        for (int j = 0; j < 4; ++j)
          acc[i][j] = __builtin_amdgcn_mfma_f32_16x16x32_bf16(af[i], bfr[j], acc[i][j], 0, 0, 0);
    }
    __syncthreads();
  }

  float* Sp = Spart + ((size_t)ks * NBH + bh) * (DKc * DVc);
#pragma unroll
  for (int i = 0; i < 4; ++i) {
    int row0 = wm * 64 + i * 16 + quad * 4;  // kd
#pragma unroll
    for (int j = 0; j < 4; ++j) {
      int col = bn * 128 + wn * 64 + j * 16 + lrow;  // vv
#pragma unroll
      for (int rg = 0; rg < 4; ++rg)
        Sp[(size_t)(row0 + rg) * DVc + col] = acc[i][j][rg];
    }
  }
}

// ------------- out = S0*eBtot + sum_ks Spart -------------
__global__ __launch_bounds__(256) void reduce_kernel(const float* __restrict__ Spart,
                                                     const float* __restrict__ eBtot,
                                                     const float* __restrict__ S0,
                                                     float* __restrict__ out) {
  int i4 = blockIdx.x * 256 + threadIdx.x;
  int idx = i4 * 4;
  int bh = idx >> 15;
  int kd = (idx >> 8) & 127;
  float e = eBtot[bh * DKc + kd];
  float4 a = ((const float4*)S0)[i4];
  float4 p0 = ((const float4*)Spart)[i4];
  float4 p1 = ((const float4*)Spart)[i4 + 262144];
  float4 p2 = ((const float4*)Spart)[i4 + 524288];
  float4 p3 = ((const float4*)Spart)[i4 + 786432];
  float4 r;
  r.x = a.x * e + p0.x + p1.x + p2.x + p3.x;
  r.y = a.y * e + p0.y + p1.y + p2.y + p3.y;
  r.z = a.z * e + p0.z + p1.z + p2.z + p3.z;
  r.w = a.w * e + p0.w + p1.w + p2.w + p3.w;
  ((float4*)out)[i4] = r;
}

// ------------- chunk gate sums: L[bh][n][kd] = sum_c logsig(g1@Wg2col + b)/GLN -------------
__global__ __launch_bounds__(128) void chunksum_kernel(const float* __restrict__ g1,
                                                       const float* __restrict__ Wg2,
                                                       const float* __restrict__ bg2,
                                                       float* __restrict__ L) {
  int n = blockIdx.x, bh = blockIdx.y;
  int b = bh >> 3, h = bh & 7;
  int t = threadIdx.x;  // kd
  int kdg = h * DKc + t;
  int trow = b * Tt + n * CHUNKc;
  __shared__ float g1s[CHUNKc * 16];
#pragma unroll
  for (int i = 0; i < 8; ++i) {
    int flat = i * 128 + t;
    int c = flat >> 4, r = flat & 15;
    g1s[flat] = g1[(size_t)(trow + c) * 128 + r];
  }
  float wc[16];
#pragma unroll
  for (int r = 0; r < 16; ++r) wc[r] = Wg2[r * KDIM + kdg];
  float bias = bg2[kdg];
  __syncthreads();
  float sum = 0.f;
  for (int c = 0; c < CHUNKc; ++c) {
    float dot = bias;
#pragma unroll
    for (int r = 0; r < 16; ++r) dot = fmaf(g1s[c * 16 + r], wc[r], dot);
    sum += logsig(dot) * (1.0f / GLNf);
  }
  L[((size_t)bh * NCHUNK + n) * DKc + t] = sum;
}

// ------------- weights: kwT[bh][kd][t] = bf16(k * exp(Btot - B_t)) in place; eBtot -------------
__global__ __launch_bounds__(128) void weight_kernel(const float* __restrict__ g1,
                                                     const float* __restrict__ Wg2,
                                                     const float* __restrict__ bg2,
                                                     const float* __restrict__ L,
                                                     ushort* __restrict__ kwT,
                                                     float* __restrict__ eBtot) {
  int n = blockIdx.x, bh = blockIdx.y;
  int b = bh >> 3, h = bh & 7;
  int t = threadIdx.x;  // kd
  int kdg = h * DKc + t;
  int trow = b * Tt + n * CHUNKc;
  __shared__ float g1s[CHUNKc * 16];
#pragma unroll
  for (int i = 0; i < 8; ++i) {
    int flat = i * 128 + t;
    int c = flat >> 4, r = flat & 15;
    g1s[flat] = g1[(size_t)(trow + c) * 128 + r];
  }
  float wc[16];
#pragma unroll
  for (int r = 0; r < 16; ++r) wc[r] = Wg2[r * KDIM + kdg];
  float bias = bg2[kdg];

  float suffix = 0.f, Ln = 0.f, Btot = 0.f;
#pragma unroll
  for (int m = 0; m < NCHUNK; ++m) {
    float Lm = L[((size_t)bh * NCHUNK + m) * DKc + t];
    if (m > n) suffix += Lm;
    if (m == n) Ln = Lm;
    Btot += Lm;
  }
  if (n == 0) eBtot[bh * DKc + t] = __expf(Btot);
  __syncthreads();

  float run = 0.f;
  size_t obase = ((size_t)bh * DKc + t) * (size_t)Tt + (size_t)n * CHUNKc;
  for (int cg = 0; cg < 8; ++cg) {
    ushort8v kw8;
    ushort8v k8 = *(const ushort8v*)(kwT + obase + cg * 8);
#pragma unroll
    for (int j = 0; j < 8; ++j) {
      int c = cg * 8 + j;
      float dot = bias;
#pragma unroll
      for (int r = 0; r < 16; ++r) dot = fmaf(g1s[c * 16 + r], wc[r], dot);
      run += logsig(dot) * (1.0f / GLNf);
      float w = __expf(suffix + Ln - run);  // exponent <= 0 always
      kw8[j] = f2bf(bf2f(k8[j]) * w);
    }
    *(ushort8v*)(kwT + obase + cg * 8) = kw8;
  }
}

extern "C" void kernel_launch(void* const* d_in, const int* in_sizes, int n_in,
                              void* d_out, int out_size, void* d_ws, size_t ws_size,
                              hipStream_t stream) {
  const float* seg = (const float*)d_in[0];
  const float* norm_w = (const float*)d_in[1];
  const float* Wk = (const float*)d_in[2];
  const float* Wv = (const float*)d_in[3];
  const float* Wg1 = (const float*)d_in[4];
  const float* Wg2 = (const float*)d_in[5];
  const float* bg2 = (const float*)d_in[6];
  const float* S0 = (const float*)d_in[7];
  float* out = (float*)d_out;
  char* ws = (char*)d_ws;

  // ---- workspace 93.65 MiB (proven available R6-R14) — exact R12/R14 layout ----
  // regA 32MiB: xb bf16[8192][2048] -> (dead after gemm_kg + transpose_x) Y bf16[32][128][2048]
  // regB 32MiB: xT bf16[4][2048][2048]
  // regD 16MiB: kT bf16[32][128][2048] -> kwT (in-place RMW) -> (dead after gemm_y)
  //             Spart f32[4][32][128][256]
  // regC 12.5MiB: W_allT bf16[3200][2048]; then Lbuf f32[32][32][128], eBtot f32[32][128]
  // d_out: g1 f32[8192][128] (dead before reduce writes d_out)
  char* regA = ws;
  char* regB = ws + (size_t)32 * 1024 * 1024;
  char* regD = ws + (size_t)64 * 1024 * 1024;
  char* regC = ws + (size_t)80 * 1024 * 1024;
  float* Lbuf = (float*)(regC + 13107200);
  float* eBtot = (float*)(regC + 13107200 + 524288);

  ushort* xb = (ushort*)regA;
  ushort* Y = (ushort*)regA;                   // after xb dead
  ushort* xT = (ushort*)regB;
  ushort* kwT = (ushort*)regD;
  float* Spart = (float*)regD;                 // after kwT dead (post gemm_y)
  ushort* Wall = (ushort*)regC;
  ushort* Wallk = Wall + (size_t)2048 * 2048;  // rows 2048.. = [Wk^T ; Wg1^T]
  float* g1buf = (float*)d_out;

  rmsnorm_kernel<<<Mrows, 256, 0, stream>>>(seg, norm_w, xb);
  transpose_all_kernel<<<dim3(64, 100), 256, 0, stream>>>(Wv, Wk, Wg1, Wall);
  transpose_x_kernel<<<dim3(32, 32, 4), 256, 0, stream>>>(xb, xT);
  gemm_kg_kernel<<<dim3(64, 18), 256, 0, stream>>>(xb, Wallk, kwT, g1buf);
  chunksum_kernel<<<dim3(NCHUNK, NBH), 128, 0, stream>>>(g1buf, Wg2, bg2, Lbuf);
  weight_kernel<<<dim3(NCHUNK, NBH), 128, 0, stream>>>(g1buf, Wg2, bg2, Lbuf, kwT, eBtot);
  gemm_y_kernel<<<512, 256, 0, stream>>>(kwT, xT, Y);
  gemm_out_sk_kernel<<<256, 256, 0, stream>>>(Y, Wall, Spart);
  reduce_kernel<<<1024, 256, 0, stream>>>(Spart, eBtot, S0, out);
}